// Round 10
// baseline (213.062 us; speedup 1.0000x reference)
//
#include <hip/hip_runtime.h>
#include <hip/hip_bf16.h>
#include <math.h>

#define NROWS 4096
#define DDIM  512
#define TW    64                       // wave tile (64x64 C per wave)
#define NTW   (NROWS / TW)             // 64
#define NTRIW (NTW * (NTW + 1) / 2)    // 2080 upper-triangle wave tiles
#define NBLKS (NTRIW / 4)              // 520 blocks x 4 waves (520 % 8 == 0)

static constexpr float ALPHA = 10.0f;
static constexpr float BETA  = 2.0f;
static constexpr float BASE  = 0.5f;

typedef short bf16x8 __attribute__((ext_vector_type(8)));
typedef float f32x4 __attribute__((ext_vector_type(4)));

// ---- sortable-uint encoding for float atomic min/max ----
__device__ __forceinline__ unsigned enc_f32(float f) {
  unsigned b = __float_as_uint(f);
  return (b & 0x80000000u) ? ~b : (b | 0x80000000u);
}
__device__ __forceinline__ float dec_f32(unsigned u) {
  unsigned b = (u & 0x80000000u) ? (u & 0x7fffffffu) : ~u;
  return __uint_as_float(b);
}
__device__ __forceinline__ unsigned f2bf(float f) {
  __hip_bfloat16 h = __float2bfloat16(f);  // RNE
  return (unsigned)*reinterpret_cast<unsigned short*>(&h);
}

// ---- convert X f32 -> bf16 packed; init min/max, ps/ns, lacc ----
__global__ __launch_bounds__(256) void convert_init_k(
    const float* __restrict__ X, unsigned short* __restrict__ Xb,
    unsigned* __restrict__ minb, unsigned* __restrict__ maxb,
    float* __restrict__ ps, float* __restrict__ ns, float* __restrict__ lacc) {
  const int gid = blockIdx.x * 256 + threadIdx.x;
  if (gid < NROWS) {
    minb[gid] = 0xFF800000u;  // enc(+inf)
    maxb[gid] = 0x007FFFFFu;  // enc(-inf)
    ps[gid] = 0.0f;
    ns[gid] = 0.0f;
  }
  if (gid < 8) lacc[gid] = 0.0f;

  const int wid = threadIdx.x >> 6, lane = threadIdx.x & 63;
  const int r = blockIdx.x * 4 + wid;
  const size_t base = (size_t)r * DDIM + lane * 8;
  const float4 v0 = *reinterpret_cast<const float4*>(X + base);
  const float4 v1 = *reinterpret_cast<const float4*>(X + base + 4);
  uint4 u;
  u.x = f2bf(v0.x) | (f2bf(v0.y) << 16);
  u.y = f2bf(v0.z) | (f2bf(v0.w) << 16);
  u.z = f2bf(v1.x) | (f2bf(v1.y) << 16);
  u.w = f2bf(v1.z) | (f2bf(v1.w) << 16);
  *reinterpret_cast<uint4*>(Xb + base) = u;
}

// ---- LDS-free wave-tile GEMM over the triangle. Each wave computes a 64x64
//      C tile via per-lane global loads (L2-resident Xb) + MFMA; no barriers.
//      PASS 0: min(pos)/max(neg) atomics. PASS 1: exp-sums + last-row stats. ----
template <int PASS>
__global__ __launch_bounds__(256) void gemm_direct(
    const unsigned short* __restrict__ Xb, const int* __restrict__ tgt,
    unsigned* __restrict__ minb, unsigned* __restrict__ maxb,
    float* __restrict__ ps, float* __restrict__ ns,
    float* __restrict__ lacc, const float* __restrict__ marginp) {
  const int tid = threadIdx.x;
  const int w = tid >> 6, lane = tid & 63;
  const int g = lane >> 4, q = lane & 15;

  // XCD-bijective chunked swizzle (520 % 8 == 0), 4 consecutive tiles/block
  const int swz = (blockIdx.x & 7) * (NBLKS / 8) + (blockIdx.x >> 3);
  int kk0 = swz * 4 + w, ti = 0;
  while (kk0 >= NTW - ti) { kk0 -= NTW - ti; ++ti; }
  const int tj = ti + kk0;
  const int i0 = ti * TW, j0 = tj * TW;
  const bool diagt = (ti == tj);

  f32x4 acc[4][4];
  #pragma unroll
  for (int m = 0; m < 4; ++m)
    #pragma unroll
    for (int n = 0; n < 4; ++n) acc[m][n] = (f32x4)0.0f;

  // per-lane fragment bases: lane (q,g) covers row (.. + q), k-chunk g*8
  const unsigned short* Ab = Xb + (size_t)(i0 + q) * DDIM + g * 8;
  const unsigned short* Bb = Xb + (size_t)(j0 + q) * DDIM + g * 8;

  for (int ks = 0; ks < DDIM / 32; ++ks) {  // 16 K-steps, no sync anywhere
    bf16x8 a[4], b[4];
    #pragma unroll
    for (int fm = 0; fm < 4; ++fm)
      a[fm] = *reinterpret_cast<const bf16x8*>(Ab + fm * 16 * DDIM + ks * 32);
    #pragma unroll
    for (int fn = 0; fn < 4; ++fn)
      b[fn] = *reinterpret_cast<const bf16x8*>(Bb + fn * 16 * DDIM + ks * 32);
    #pragma unroll
    for (int fm = 0; fm < 4; ++fm)
      #pragma unroll
      for (int fn = 0; fn < 4; ++fn)
        acc[fm][fn] = __builtin_amdgcn_mfma_f32_16x16x32_bf16(a[fm], b[fn], acc[fm][fn], 0, 0, 0);
  }

  // ---- epilogue indices ----
  int tj4[4], ti16[16];
  #pragma unroll
  for (int fn = 0; fn < 4; ++fn) tj4[fn] = tgt[j0 + fn * 16 + q];
  #pragma unroll
  for (int fm = 0; fm < 4; ++fm)
    #pragma unroll
    for (int reg = 0; reg < 4; ++reg)
      ti16[fm * 4 + reg] = tgt[i0 + fm * 16 + g * 4 + reg];

  if constexpr (PASS == 0) {
    // row-side min(pos)/max(neg)  [R2-verified]
    #pragma unroll
    for (int fm = 0; fm < 4; ++fm) {
      #pragma unroll
      for (int reg = 0; reg < 4; ++reg) {
        const int lr = fm * 16 + g * 4 + reg;
        const int r = i0 + lr;
        const int tr = ti16[fm * 4 + reg];
        float mnp = INFINITY, mxn = -INFINITY;
        #pragma unroll
        for (int fn = 0; fn < 4; ++fn) {
          float s = acc[fm][fn][reg];
          if (diagt && lr == fn * 16 + q) s = 1.0f;  // diag: excluded by s<1.0
          if (tj4[fn] == tr) {
            if (s < 1.0f) mnp = fminf(mnp, s);
          } else {
            mxn = fmaxf(mxn, s);
          }
        }
        #pragma unroll
        for (int off = 1; off < 16; off <<= 1) {
          mnp = fminf(mnp, __shfl_xor(mnp, off));
          mxn = fmaxf(mxn, __shfl_xor(mxn, off));
        }
        if (q == 0) {
          if (mnp != INFINITY) atomicMin(minb + r, enc_f32(mnp));
          if (mxn != -INFINITY) atomicMax(maxb + r, enc_f32(mxn));
        }
      }
    }
    if (!diagt) {  // col-side  [R4-verified]
      #pragma unroll
      for (int fn = 0; fn < 4; ++fn) {
        const int tc = tj4[fn];
        float mnp = INFINITY, mxn = -INFINITY;
        #pragma unroll
        for (int fm = 0; fm < 4; ++fm)
          #pragma unroll
          for (int reg = 0; reg < 4; ++reg) {
            const float s = acc[fm][fn][reg];
            if (ti16[fm * 4 + reg] == tc) {
              if (s < 1.0f) mnp = fminf(mnp, s);
            } else {
              mxn = fmaxf(mxn, s);
            }
          }
        mnp = fminf(mnp, __shfl_xor(mnp, 16));
        mnp = fminf(mnp, __shfl_xor(mnp, 32));
        mxn = fmaxf(mxn, __shfl_xor(mxn, 16));
        mxn = fmaxf(mxn, __shfl_xor(mxn, 32));
        if (lane < 16) {
          if (mnp != INFINITY) atomicMin(minb + j0 + fn * 16 + q, enc_f32(mnp));
          if (mxn != -INFINITY) atomicMax(maxb + j0 + fn * 16 + q, enc_f32(mxn));
        }
      }
    }
  } else {
    // PASS 1: exp-sums + last-row stats  [R4-verified logic]
    const float margin = *marginp;
    float mpr[16], mxr[16];
    #pragma unroll
    for (int fm = 0; fm < 4; ++fm)
      #pragma unroll
      for (int reg = 0; reg < 4; ++reg) {
        const int r = i0 + fm * 16 + g * 4 + reg;
        mpr[fm * 4 + reg] = dec_f32(minb[r]);
        mxr[fm * 4 + reg] = dec_f32(maxb[r]);
      }
    float mpc[4], mxc[4], cps[4], cns[4];
    #pragma unroll
    for (int fn = 0; fn < 4; ++fn) {
      mpc[fn] = dec_f32(minb[j0 + fn * 16 + q]);
      mxc[fn] = dec_f32(maxb[j0 + fn * 16 + q]);
      cps[fn] = 0.0f; cns[fn] = 0.0f;
    }
    float wlsp = 0, wlcp = 0, wlsn = 0, wlcn = 0;  // last row, row-side
    float clsp = 0, clcp = 0, clsn = 0, clcn = 0;  // last row, col-side
    const bool anycollast = (!diagt) && (tj == NTW - 1);

    #pragma unroll
    for (int fm = 0; fm < 4; ++fm) {
      #pragma unroll
      for (int reg = 0; reg < 4; ++reg) {
        const int idx = fm * 4 + reg;
        const int lr = fm * 16 + g * 4 + reg;
        const int r = i0 + lr;
        const int tr = ti16[idx];
        const bool lastrow = (r == NROWS - 1);
        float rps = 0.0f, rns = 0.0f;
        #pragma unroll
        for (int fn = 0; fn < 4; ++fn) {
          float s = acc[fm][fn][reg];
          if (diagt && lr == fn * 16 + q) s = 1.0f;  // diag -> excluded
          const bool collast = anycollast && (fn == 3) && (q == 15);
          if (tj4[fn] != tr) {
            const float en = __expf(ALPHA * (s - BASE));
            if (s + margin - mpr[idx] > 0.0f) rns += en;
            if (!diagt && s + margin - mpc[fn] > 0.0f) cns[fn] += en;
            if (lastrow) { wlsn += s; wlcn += 1.0f; }
            if (collast) { clsn += s; clcn += 1.0f; }
          } else if (s < 1.0f) {
            const float ep = __expf(-BETA * (s - BASE));
            if (mxr[idx] - s + margin > 0.0f) rps += ep;
            if (!diagt && mxc[fn] - s + margin > 0.0f) cps[fn] += ep;
            if (lastrow) { wlsp += s; wlcp += 1.0f; }
            if (collast) { clsp += s; clcp += 1.0f; }
          }
        }
        #pragma unroll
        for (int off = 1; off < 16; off <<= 1) {
          rps += __shfl_xor(rps, off);
          rns += __shfl_xor(rns, off);
        }
        if (q == 0) {
          if (rps != 0.0f) atomicAdd(ps + r, rps);
          if (rns != 0.0f) atomicAdd(ns + r, rns);
        }
      }
    }
    // last-row row-side: row 4095 lives only in diag tile (63,63)
    if (diagt && ti == NTW - 1) {
      #pragma unroll
      for (int off = 1; off < 16; off <<= 1) {
        wlsp += __shfl_xor(wlsp, off); wlcp += __shfl_xor(wlcp, off);
        wlsn += __shfl_xor(wlsn, off); wlcn += __shfl_xor(wlcn, off);
      }
      if (lane == 48) {  // g==3, q==0 holds row 4095's group sum
        if (wlcp != 0.0f) { atomicAdd(lacc + 0, wlsp); atomicAdd(lacc + 1, wlcp); }
        if (wlcn != 0.0f) { atomicAdd(lacc + 2, wlsn); atomicAdd(lacc + 3, wlcn); }
      }
    }
    if (!diagt) {
      #pragma unroll
      for (int fn = 0; fn < 4; ++fn) {
        float v1 = cps[fn], v2 = cns[fn];
        v1 += __shfl_xor(v1, 16); v1 += __shfl_xor(v1, 32);
        v2 += __shfl_xor(v2, 16); v2 += __shfl_xor(v2, 32);
        if (lane < 16) {
          if (v1 != 0.0f) atomicAdd(ps + j0 + fn * 16 + q, v1);
          if (v2 != 0.0f) atomicAdd(ns + j0 + fn * 16 + q, v2);
        }
      }
      if (anycollast) {  // col 4095: fn==3, q==15 lanes
        clsp += __shfl_xor(clsp, 16); clsp += __shfl_xor(clsp, 32);
        clcp += __shfl_xor(clcp, 16); clcp += __shfl_xor(clcp, 32);
        clsn += __shfl_xor(clsn, 16); clsn += __shfl_xor(clsn, 32);
        clcn += __shfl_xor(clcn, 16); clcn += __shfl_xor(clcn, 32);
        if (lane == 15) {
          if (clcp != 0.0f) { atomicAdd(lacc + 0, clsp); atomicAdd(lacc + 1, clcp); }
          if (clcn != 0.0f) { atomicAdd(lacc + 2, clsn); atomicAdd(lacc + 3, clcn); }
        }
      }
    }
  }
}

__device__ __forceinline__ float block_sum(float v) {
  __shared__ float sh[4];
  #pragma unroll
  for (int off = 32; off > 0; off >>= 1) v += __shfl_down(v, off);
  if ((threadIdx.x & 63) == 0) sh[threadIdx.x >> 6] = v;
  __syncthreads();
  float r = sh[0] + sh[1] + sh[2] + sh[3];
  __syncthreads();
  return r;
}

__global__ __launch_bounds__(256) void finalize_k(
    const float* __restrict__ ps, const float* __restrict__ ns,
    const float* __restrict__ lacc, float* __restrict__ out) {
  float lsum = 0.0f, inval = 0.0f;
  #pragma unroll
  for (int c = 0; c < 16; ++c) {
    const int i = c * 256 + threadIdx.x;
    const float p = ps[i], n = ns[i];
    if (p > 0.0f && n > 0.0f) {
      lsum += (2.0f / BETA) * log1pf(p) + (2.0f / ALPHA) * log1pf(n);
    } else {
      inval += 1.0f;
    }
  }
  lsum = block_sum(lsum);
  inval = block_sum(inval);
  if (threadIdx.x == 0) {
    out[0] = lsum / (float)NROWS;
    out[1] = inval / (float)NROWS;
    out[2] = lacc[0] / fmaxf(lacc[1], 1.0f);
    out[3] = lacc[2] / fmaxf(lacc[3], 1.0f);
  }
}

extern "C" void kernel_launch(void* const* d_in, const int* in_sizes, int n_in,
                              void* d_out, int out_size, void* d_ws, size_t ws_size,
                              hipStream_t stream) {
  const float* X = (const float*)d_in[0];
  const int* tgt = (const int*)d_in[1];
  const float* marginp = (const float*)d_in[2];
  float* out = (float*)d_out;

  char* ws = (char*)d_ws;
  unsigned* minb = (unsigned*)ws;                 // @0     16 KB
  unsigned* maxb = (unsigned*)(ws + (16 << 10));  // @16K   16 KB
  float* ps = (float*)(ws + (32 << 10));          // @32K   16 KB
  float* ns = (float*)(ws + (48 << 10));          // @48K   16 KB
  float* lacc = (float*)(ws + (64 << 10));        // @64K   small
  unsigned short* Xb = (unsigned short*)(ws + (128 << 10));  // 4 MB

  convert_init_k<<<dim3(NROWS / 4), 256, 0, stream>>>(X, Xb, minb, maxb, ps, ns, lacc);
  gemm_direct<0><<<dim3(NBLKS), 256, 0, stream>>>(Xb, tgt, minb, maxb, ps, ns, lacc, marginp);
  gemm_direct<1><<<dim3(NBLKS), 256, 0, stream>>>(Xb, tgt, minb, maxb, ps, ns, lacc, marginp);
  finalize_k<<<dim3(1), 256, 0, stream>>>(ps, ns, lacc, out);
}

// Round 12
// 110.185 us; speedup vs baseline: 1.9337x; 1.9337x over previous
//
#include <hip/hip_runtime.h>
#include <hip/hip_bf16.h>
#include <math.h>

#define NROWS 4096
#define DDIM  512
#define BM    128
#define BK    128
#define NT    (DDIM / BK)              // 4 K-steps
#define NBLK  (NROWS / BM)             // 32
#define NTRI  (NBLK * (NBLK + 1) / 2)  // 528 upper-triangle tiles (528 % 8 == 0)

static constexpr float ALPHA = 10.0f;
static constexpr float BETA  = 2.0f;
static constexpr float BASE  = 0.5f;

typedef short bf16x8 __attribute__((ext_vector_type(8)));
typedef float f32x4 __attribute__((ext_vector_type(4)));

__device__ __forceinline__ unsigned f2bf(float f) {
  __hip_bfloat16 h = __float2bfloat16(f);  // RNE
  return (unsigned)*reinterpret_cast<unsigned short*>(&h);
}
__device__ __forceinline__ float bf2f(unsigned short u) {
  return __uint_as_float(((unsigned)u) << 16);
}

#define GLOAD_LDS16(g, l)                                              \
  __builtin_amdgcn_global_load_lds(                                    \
      (const __attribute__((address_space(1))) void*)(g),              \
      (__attribute__((address_space(3))) void*)(l), 16, 0, 0)

// ---- convert X f32 -> bf16 packed (wave-per-row) ----
__global__ __launch_bounds__(256) void convert_k(const float* __restrict__ X,
                                                 unsigned short* __restrict__ Xb) {
  const int wid = threadIdx.x >> 6, lane = threadIdx.x & 63;
  const int r = blockIdx.x * 4 + wid;
  const size_t base = (size_t)r * DDIM + lane * 8;
  const float4 v0 = *reinterpret_cast<const float4*>(X + base);
  const float4 v1 = *reinterpret_cast<const float4*>(X + base + 4);
  uint4 u;
  u.x = f2bf(v0.x) | (f2bf(v0.y) << 16);
  u.y = f2bf(v0.z) | (f2bf(v0.w) << 16);
  u.z = f2bf(v1.x) | (f2bf(v1.y) << 16);
  u.w = f2bf(v1.z) | (f2bf(v1.w) << 16);
  *reinterpret_cast<uint4*>(Xb + base) = u;
}

// ---- triangle 128x128 MFMA GEMM, BK=128 (4 steps, 8 barriers/block),
//      XOR-swizzled LDS (linear dest + pre-swizzled global src + swz read),
//      coalesced bf16 stores of both orientations via LDS transpose.
//      Diagonal elements stored as bf16 1.0 (R7-verified semantics). ----
__global__ __launch_bounds__(256) void gemm_tri_store(
    const unsigned short* __restrict__ Xb, unsigned short* __restrict__ simb) {
  __shared__ unsigned short lds[2][BM * BK] __attribute__((aligned(16)));  // 64 KB

  // XCD-bijective swizzle (528 % 8 == 0)
  const int bswz = (blockIdx.x & 7) * (NTRI / 8) + (blockIdx.x >> 3);
  int kk0 = bswz, bi = 0;
  while (kk0 >= NBLK - bi) { kk0 -= NBLK - bi; ++bi; }
  const int bj = bi + kk0;
  const int i0 = bi * BM, j0 = bj * BM;
  const bool diagb = (bi == bj);

  const int tid = threadIdx.x;
  const int w = tid >> 6, lane = tid & 63;
  const int wr = w >> 1, wc = w & 1;
  const int g = lane >> 4, q = lane & 15;
  const char* Xbb = (const char*)Xb;

  f32x4 acc[4][4];
  #pragma unroll
  for (int m = 0; m < 4; ++m)
    #pragma unroll
    for (int n = 0; n < 4; ++n) acc[m][n] = (f32x4)0.0f;

  for (int t = 0; t < NT; ++t) {
    // stage A (and B when off-diag): 32 KB/panel; source pre-swizzled so
    // linear LDS + swizzled ds_read is conflict-free (rule #21)
    {
      const int kb = t * (BK * 2);
      #pragma unroll
      for (int c = 0; c < 8; ++c) {
        const int lin = (c * 256 + tid) * 16;      // byte offset in panel
        const int row = lin >> 8;                  // 256 B per row
        const int col = lin & 255;
        const int scol = col ^ ((row & 15) << 4);
        GLOAD_LDS16(Xbb + (size_t)(i0 + row) * (DDIM * 2) + kb + scol,
                    (char*)&lds[0][0] + lin);
        if (!diagb)
          GLOAD_LDS16(Xbb + (size_t)(j0 + row) * (DDIM * 2) + kb + scol,
                      (char*)&lds[1][0] + lin);
      }
    }
    __syncthreads();  // drain staging
    const char* Ab = (const char*)&lds[0][0];
    const char* Bb = diagb ? Ab : (const char*)&lds[1][0];
    #pragma unroll
    for (int kk = 0; kk < 4; ++kk) {
      bf16x8 a[4], b[4];
      #pragma unroll
      for (int fm = 0; fm < 4; ++fm) {
        const int row = wr * 64 + fm * 16 + q;
        const int colb = (kk * 64 + g * 16) ^ ((row & 15) << 4);
        a[fm] = *reinterpret_cast<const bf16x8*>(Ab + row * 256 + colb);
      }
      #pragma unroll
      for (int fn = 0; fn < 4; ++fn) {
        const int row = wc * 64 + fn * 16 + q;
        const int colb = (kk * 64 + g * 16) ^ ((row & 15) << 4);
        b[fn] = *reinterpret_cast<const bf16x8*>(Bb + row * 256 + colb);
      }
      #pragma unroll
      for (int fm = 0; fm < 4; ++fm)
        #pragma unroll
        for (int fn = 0; fn < 4; ++fn)
          acc[fm][fn] = __builtin_amdgcn_mfma_f32_16x16x32_bf16(a[fm], b[fn], acc[fm][fn], 0, 0, 0);
    }
    __syncthreads();  // reads done before next stage overwrites
  }

  // ---- store epilogue (R7-verified): 4 rounds of 32 rows per orientation,
  //      staged in LDS view 32 x 136 ushort ----
  unsigned short* SV = &lds[0][0];
  #pragma unroll
  for (int orient = 0; orient < 2; ++orient) {
    if (orient == 1 && diagb) break;
    for (int d = 0; d < 4; ++d) {
      if (orient == 0) {
        if (wr == (d >> 1)) {
          #pragma unroll
          for (int h = 0; h < 2; ++h) {
            const int fm = 2 * (d & 1) + h;
            #pragma unroll
            for (int fn = 0; fn < 4; ++fn)
              #pragma unroll
              for (int reg = 0; reg < 4; ++reg) {
                const int shrow = h * 16 + g * 4 + reg;
                const int col = wc * 64 + fn * 16 + q;
                unsigned short v = (unsigned short)f2bf(acc[fm][fn][reg]);
                if (diagb && (32 * d + shrow == col)) v = 0x3F80;  // diag = 1.0
                SV[shrow * 136 + col] = v;
              }
          }
        }
      } else {
        if (wc == (d >> 1)) {
          #pragma unroll
          for (int h = 0; h < 2; ++h) {
            const int fn = 2 * (d & 1) + h;
            const int shrow = h * 16 + q;
            #pragma unroll
            for (int fm = 0; fm < 4; ++fm) {
              const int colR = wr * 64 + fm * 16 + g * 4;
              uint2 uu;
              uu.x = f2bf(acc[fm][fn][0]) | (f2bf(acc[fm][fn][1]) << 16);
              uu.y = f2bf(acc[fm][fn][2]) | (f2bf(acc[fm][fn][3]) << 16);
              *reinterpret_cast<uint2*>(&SV[shrow * 136 + colR]) = uu;
            }
          }
        }
      }
      __syncthreads();
      #pragma unroll
      for (int rr = 0; rr < 2; ++rr) {
        const int s = tid + rr * 256;
        const int row = s >> 4, cs = s & 15;
        const bf16x8 vv = *reinterpret_cast<const bf16x8*>(&SV[row * 136 + cs * 8]);
        unsigned short* dst =
            (orient == 0)
                ? simb + (size_t)(i0 + d * 32 + row) * NROWS + j0 + cs * 8
                : simb + (size_t)(j0 + d * 32 + row) * NROWS + i0 + cs * 8;
        *reinterpret_cast<bf16x8*>(dst) = vv;
      }
      __syncthreads();
    }
  }
}

// ---- wave-per-row: read row once into regs; phase A min/max + class mask;
//      phase B exp-sums + last-row pre-mining stats. No atomics. (R7) ----
__global__ __launch_bounds__(256) void rows_k(
    const unsigned short* __restrict__ simb, const int* __restrict__ tgt,
    const float* __restrict__ marginp, float* __restrict__ rowloss,
    float* __restrict__ rowvalid, float* __restrict__ lacc) {
  __shared__ int tgl[NROWS];  // 16 KB
  const int tid = threadIdx.x;
  #pragma unroll
  for (int c = 0; c < 4; ++c)
    reinterpret_cast<int4*>(tgl)[tid + c * 256] =
        reinterpret_cast<const int4*>(tgt)[tid + c * 256];
  __syncthreads();

  const int wid = tid >> 6, lane = tid & 63;
  const int i = blockIdx.x * 4 + wid;
  const int ti = tgl[i];
  const unsigned short* row = simb + (size_t)i * NROWS;
  const bool lastw = (i == NROWS - 1);

  bf16x8 v[8];
  unsigned long long same = 0ull;
  float minp = INFINITY, maxn = -INFINITY;
  #pragma unroll
  for (int c = 0; c < 8; ++c) {
    const int j0 = c * 512 + lane * 8;
    v[c] = *reinterpret_cast<const bf16x8*>(row + j0);
    const int4 t0 = *reinterpret_cast<const int4*>(tgl + j0);
    const int4 t1 = *reinterpret_cast<const int4*>(tgl + j0 + 4);
    const int tj[8] = {t0.x, t0.y, t0.z, t0.w, t1.x, t1.y, t1.z, t1.w};
    #pragma unroll
    for (int e = 0; e < 8; ++e) {
      const float s = bf2f((unsigned short)v[c][e]);
      const bool sm = (tj[e] == ti);
      same |= (unsigned long long)sm << (c * 8 + e);
      if (sm) {
        if (s < 1.0f) minp = fminf(minp, s);
      } else {
        maxn = fmaxf(maxn, s);
      }
    }
  }
  #pragma unroll
  for (int off = 1; off < 64; off <<= 1) {
    minp = fminf(minp, __shfl_xor(minp, off));
    maxn = fmaxf(maxn, __shfl_xor(maxn, off));
  }

  const float margin = *marginp;
  float psum = 0.0f, nsum = 0.0f;
  float lsp = 0.0f, lcp = 0.0f, lsn = 0.0f, lcn = 0.0f;
  #pragma unroll
  for (int c = 0; c < 8; ++c) {
    #pragma unroll
    for (int e = 0; e < 8; ++e) {
      const float s = bf2f((unsigned short)v[c][e]);
      const bool sm = (same >> (c * 8 + e)) & 1ull;
      if (!sm) {
        if (s + margin - minp > 0.0f) nsum += __expf(ALPHA * (s - BASE));
        if (lastw) { lsn += s; lcn += 1.0f; }
      } else if (s < 1.0f) {
        if (maxn - s + margin > 0.0f) psum += __expf(-BETA * (s - BASE));
        if (lastw) { lsp += s; lcp += 1.0f; }
      }
    }
  }
  #pragma unroll
  for (int off = 1; off < 64; off <<= 1) {
    psum += __shfl_xor(psum, off);
    nsum += __shfl_xor(nsum, off);
  }
  if (lastw) {
    #pragma unroll
    for (int off = 1; off < 64; off <<= 1) {
      lsp += __shfl_xor(lsp, off); lcp += __shfl_xor(lcp, off);
      lsn += __shfl_xor(lsn, off); lcn += __shfl_xor(lcn, off);
    }
  }
  if (lane == 0) {
    const bool valid = (psum > 0.0f) && (nsum > 0.0f);
    rowloss[i] = valid ? (2.0f / BETA) * log1pf(psum) + (2.0f / ALPHA) * log1pf(nsum) : 0.0f;
    rowvalid[i] = valid ? 0.0f : 1.0f;
    if (lastw) { lacc[0] = lsp; lacc[1] = lcp; lacc[2] = lsn; lacc[3] = lcn; }
  }
}

__device__ __forceinline__ float block_sum(float v) {
  __shared__ float sh[4];
  #pragma unroll
  for (int off = 32; off > 0; off >>= 1) v += __shfl_down(v, off);
  if ((threadIdx.x & 63) == 0) sh[threadIdx.x >> 6] = v;
  __syncthreads();
  float r = sh[0] + sh[1] + sh[2] + sh[3];
  __syncthreads();
  return r;
}

__global__ __launch_bounds__(256) void finalize_k(
    const float* __restrict__ rowloss, const float* __restrict__ rowvalid,
    const float* __restrict__ lacc, float* __restrict__ out) {
  float lsum = 0.0f, inval = 0.0f;
  #pragma unroll
  for (int c = 0; c < 16; ++c) {
    const int i = c * 256 + threadIdx.x;
    lsum += rowloss[i];
    inval += rowvalid[i];
  }
  lsum = block_sum(lsum);
  inval = block_sum(inval);
  if (threadIdx.x == 0) {
    out[0] = lsum / (float)NROWS;
    out[1] = inval / (float)NROWS;
    out[2] = lacc[0] / fmaxf(lacc[1], 1.0f);
    out[3] = lacc[2] / fmaxf(lacc[3], 1.0f);
  }
}

extern "C" void kernel_launch(void* const* d_in, const int* in_sizes, int n_in,
                              void* d_out, int out_size, void* d_ws, size_t ws_size,
                              hipStream_t stream) {
  const float* X = (const float*)d_in[0];
  const int* tgt = (const int*)d_in[1];
  const float* marginp = (const float*)d_in[2];
  float* out = (float*)d_out;

  char* ws = (char*)d_ws;
  float* rowloss = (float*)ws;                    // @0     16 KB
  float* rowvalid = (float*)(ws + (16 << 10));    // @16K   16 KB
  float* lacc = (float*)(ws + (32 << 10));        // @32K   small
  unsigned short* Xb = (unsigned short*)(ws + (128 << 10));  // 4 MB
  unsigned short* simb = (unsigned short*)(ws + (128 << 10) + ((size_t)4 << 20));  // 32 MB

  convert_k<<<dim3(NROWS / 4), 256, 0, stream>>>(X, Xb);
  gemm_tri_store<<<dim3(NTRI), 256, 0, stream>>>(Xb, simb);
  rows_k<<<dim3(NROWS / 4), 256, 0, stream>>>(simb, tgt, marginp, rowloss, rowvalid, lacc);
  finalize_k<<<dim3(1), 256, 0, stream>>>(rowloss, rowvalid, lacc, out);
}

// Round 13
// 108.768 us; speedup vs baseline: 1.9589x; 1.0130x over previous
//
#include <hip/hip_runtime.h>
#include <hip/hip_bf16.h>
#include <math.h>

#define NROWS 4096
#define DDIM  512
#define BM    128
#define BK    128
#define NT    (DDIM / BK)              // 4 K-steps
#define NBLK  (NROWS / BM)             // 32
#define NTRI  (NBLK * (NBLK + 1) / 2)  // 528 upper-triangle tiles (528 % 8 == 0)

static constexpr float ALPHA = 10.0f;
static constexpr float BETA  = 2.0f;
static constexpr float BASE  = 0.5f;

typedef short bf16x8 __attribute__((ext_vector_type(8)));
typedef float f32x4 __attribute__((ext_vector_type(4)));

__device__ __forceinline__ unsigned f2bf(float f) {
  __hip_bfloat16 h = __float2bfloat16(f);  // RNE
  return (unsigned)*reinterpret_cast<unsigned short*>(&h);
}
__device__ __forceinline__ float bf2f(unsigned short u) {
  return __uint_as_float(((unsigned)u) << 16);
}

#define GLOAD_LDS16(g, l)                                              \
  __builtin_amdgcn_global_load_lds(                                    \
      (const __attribute__((address_space(1))) void*)(g),              \
      (__attribute__((address_space(3))) void*)(l), 16, 0, 0)

// ---- convert X f32 -> bf16 packed (wave-per-row) ----
__global__ __launch_bounds__(256) void convert_k(const float* __restrict__ X,
                                                 unsigned short* __restrict__ Xb) {
  const int wid = threadIdx.x >> 6, lane = threadIdx.x & 63;
  const int r = blockIdx.x * 4 + wid;
  const size_t base = (size_t)r * DDIM + lane * 8;
  const float4 v0 = *reinterpret_cast<const float4*>(X + base);
  const float4 v1 = *reinterpret_cast<const float4*>(X + base + 4);
  uint4 u;
  u.x = f2bf(v0.x) | (f2bf(v0.y) << 16);
  u.y = f2bf(v0.z) | (f2bf(v0.w) << 16);
  u.z = f2bf(v1.x) | (f2bf(v1.y) << 16);
  u.w = f2bf(v1.z) | (f2bf(v1.w) << 16);
  *reinterpret_cast<uint4*>(Xb + base) = u;
}

// ---- triangle 128x128 MFMA GEMM, BK=128 (4 steps), XOR-swizzled LDS,
//      one-shot store epilogue (3 barriers): full-tile LDS staging view.
//      Diagonal elements stored as bf16 1.0 (R7/R12-verified semantics). ----
__global__ __launch_bounds__(256) void gemm_tri_store(
    const unsigned short* __restrict__ Xb, unsigned short* __restrict__ simb) {
  __shared__ unsigned short lds[2][BM * BK] __attribute__((aligned(16)));  // 64 KB

  // XCD-bijective swizzle (528 % 8 == 0)
  const int bswz = (blockIdx.x & 7) * (NTRI / 8) + (blockIdx.x >> 3);
  int kk0 = bswz, bi = 0;
  while (kk0 >= NBLK - bi) { kk0 -= NBLK - bi; ++bi; }
  const int bj = bi + kk0;
  const int i0 = bi * BM, j0 = bj * BM;
  const bool diagb = (bi == bj);

  const int tid = threadIdx.x;
  const int w = tid >> 6, lane = tid & 63;
  const int wr = w >> 1, wc = w & 1;
  const int g = lane >> 4, q = lane & 15;
  const char* Xbb = (const char*)Xb;

  f32x4 acc[4][4];
  #pragma unroll
  for (int m = 0; m < 4; ++m)
    #pragma unroll
    for (int n = 0; n < 4; ++n) acc[m][n] = (f32x4)0.0f;

  for (int t = 0; t < NT; ++t) {
    // stage A (and B when off-diag): source pre-swizzled so linear LDS +
    // swizzled ds_read is conflict-free (rule #21)
    {
      const int kb = t * (BK * 2);
      #pragma unroll
      for (int c = 0; c < 8; ++c) {
        const int lin = (c * 256 + tid) * 16;      // byte offset in panel
        const int row = lin >> 8;                  // 256 B per row
        const int col = lin & 255;
        const int scol = col ^ ((row & 15) << 4);
        GLOAD_LDS16(Xbb + (size_t)(i0 + row) * (DDIM * 2) + kb + scol,
                    (char*)&lds[0][0] + lin);
        if (!diagb)
          GLOAD_LDS16(Xbb + (size_t)(j0 + row) * (DDIM * 2) + kb + scol,
                      (char*)&lds[1][0] + lin);
      }
    }
    __syncthreads();  // drain staging
    const char* Ab = (const char*)&lds[0][0];
    const char* Bb = diagb ? Ab : (const char*)&lds[1][0];
    #pragma unroll
    for (int kk = 0; kk < 4; ++kk) {
      bf16x8 a[4], b[4];
      #pragma unroll
      for (int fm = 0; fm < 4; ++fm) {
        const int row = wr * 64 + fm * 16 + q;
        const int colb = (kk * 64 + g * 16) ^ ((row & 15) << 4);
        a[fm] = *reinterpret_cast<const bf16x8*>(Ab + row * 256 + colb);
      }
      #pragma unroll
      for (int fn = 0; fn < 4; ++fn) {
        const int row = wc * 64 + fn * 16 + q;
        const int colb = (kk * 64 + g * 16) ^ ((row & 15) << 4);
        b[fn] = *reinterpret_cast<const bf16x8*>(Bb + row * 256 + colb);
      }
      #pragma unroll
      for (int fm = 0; fm < 4; ++fm)
        #pragma unroll
        for (int fn = 0; fn < 4; ++fn)
          acc[fm][fn] = __builtin_amdgcn_mfma_f32_16x16x32_bf16(a[fm], b[fn], acc[fm][fn], 0, 0, 0);
    }
    __syncthreads();  // reads done before next stage overwrites
  }

  // ---- one-shot store epilogue: SV = 128 rows x 136 ushort (34.8 KB) ----
  unsigned short* SV = &lds[0][0];

  // orientation 0: row-major tile -> simb[i0+row][j0+col]
  #pragma unroll
  for (int fm = 0; fm < 4; ++fm)
    #pragma unroll
    for (int reg = 0; reg < 4; ++reg) {
      const int rloc = wr * 64 + fm * 16 + g * 4 + reg;
      #pragma unroll
      for (int fn = 0; fn < 4; ++fn) {
        const int cloc = wc * 64 + fn * 16 + q;
        unsigned short v = (unsigned short)f2bf(acc[fm][fn][reg]);
        if (diagb && rloc == cloc) v = 0x3F80;  // diag = 1.0
        SV[rloc * 136 + cloc] = v;
      }
    }
  __syncthreads();
  #pragma unroll
  for (int rr = 0; rr < 8; ++rr) {
    const int s = rr * 256 + tid;
    const int row = s >> 4, cs = s & 15;
    const bf16x8 vv = *reinterpret_cast<const bf16x8*>(&SV[row * 136 + cs * 8]);
    *reinterpret_cast<bf16x8*>(simb + (size_t)(i0 + row) * NROWS + j0 + cs * 8) = vv;
  }

  if (!diagb) {
    __syncthreads();  // orient-0 reads complete before overwrite
    // orientation 1: transposed tile -> simb[j0+row][i0+col]; acc regs 0..3
    // are col-adjacent in the transposed view -> packed uint2 writes
    #pragma unroll
    for (int fn = 0; fn < 4; ++fn) {
      const int shrow = wc * 64 + fn * 16 + q;
      #pragma unroll
      for (int fm = 0; fm < 4; ++fm) {
        const int colR = wr * 64 + fm * 16 + g * 4;
        uint2 uu;
        uu.x = f2bf(acc[fm][fn][0]) | (f2bf(acc[fm][fn][1]) << 16);
        uu.y = f2bf(acc[fm][fn][2]) | (f2bf(acc[fm][fn][3]) << 16);
        *reinterpret_cast<uint2*>(&SV[shrow * 136 + colR]) = uu;
      }
    }
    __syncthreads();
    #pragma unroll
    for (int rr = 0; rr < 8; ++rr) {
      const int s = rr * 256 + tid;
      const int row = s >> 4, cs = s & 15;
      const bf16x8 vv = *reinterpret_cast<const bf16x8*>(&SV[row * 136 + cs * 8]);
      *reinterpret_cast<bf16x8*>(simb + (size_t)(j0 + row) * NROWS + i0 + cs * 8) = vv;
    }
  }
}

// ---- wave-per-row: read row once into regs; phase A min/max + class mask;
//      phase B exp-sums + last-row pre-mining stats. No atomics. (R7) ----
__global__ __launch_bounds__(256) void rows_k(
    const unsigned short* __restrict__ simb, const int* __restrict__ tgt,
    const float* __restrict__ marginp, float* __restrict__ rowloss,
    float* __restrict__ rowvalid, float* __restrict__ lacc) {
  __shared__ int tgl[NROWS];  // 16 KB
  const int tid = threadIdx.x;
  #pragma unroll
  for (int c = 0; c < 4; ++c)
    reinterpret_cast<int4*>(tgl)[tid + c * 256] =
        reinterpret_cast<const int4*>(tgt)[tid + c * 256];
  __syncthreads();

  const int wid = tid >> 6, lane = tid & 63;
  const int i = blockIdx.x * 4 + wid;
  const int ti = tgl[i];
  const unsigned short* row = simb + (size_t)i * NROWS;
  const bool lastw = (i == NROWS - 1);

  bf16x8 v[8];
  unsigned long long same = 0ull;
  float minp = INFINITY, maxn = -INFINITY;
  #pragma unroll
  for (int c = 0; c < 8; ++c) {
    const int j0 = c * 512 + lane * 8;
    v[c] = *reinterpret_cast<const bf16x8*>(row + j0);
    const int4 t0 = *reinterpret_cast<const int4*>(tgl + j0);
    const int4 t1 = *reinterpret_cast<const int4*>(tgl + j0 + 4);
    const int tj[8] = {t0.x, t0.y, t0.z, t0.w, t1.x, t1.y, t1.z, t1.w};
    #pragma unroll
    for (int e = 0; e < 8; ++e) {
      const float s = bf2f((unsigned short)v[c][e]);
      const bool sm = (tj[e] == ti);
      same |= (unsigned long long)sm << (c * 8 + e);
      if (sm) {
        if (s < 1.0f) minp = fminf(minp, s);
      } else {
        maxn = fmaxf(maxn, s);
      }
    }
  }
  #pragma unroll
  for (int off = 1; off < 64; off <<= 1) {
    minp = fminf(minp, __shfl_xor(minp, off));
    maxn = fmaxf(maxn, __shfl_xor(maxn, off));
  }

  const float margin = *marginp;
  float psum = 0.0f, nsum = 0.0f;
  float lsp = 0.0f, lcp = 0.0f, lsn = 0.0f, lcn = 0.0f;
  #pragma unroll
  for (int c = 0; c < 8; ++c) {
    #pragma unroll
    for (int e = 0; e < 8; ++e) {
      const float s = bf2f((unsigned short)v[c][e]);
      const bool sm = (same >> (c * 8 + e)) & 1ull;
      if (!sm) {
        if (s + margin - minp > 0.0f) nsum += __expf(ALPHA * (s - BASE));
        if (lastw) { lsn += s; lcn += 1.0f; }
      } else if (s < 1.0f) {
        if (maxn - s + margin > 0.0f) psum += __expf(-BETA * (s - BASE));
        if (lastw) { lsp += s; lcp += 1.0f; }
      }
    }
  }
  #pragma unroll
  for (int off = 1; off < 64; off <<= 1) {
    psum += __shfl_xor(psum, off);
    nsum += __shfl_xor(nsum, off);
  }
  if (lastw) {
    #pragma unroll
    for (int off = 1; off < 64; off <<= 1) {
      lsp += __shfl_xor(lsp, off); lcp += __shfl_xor(lcp, off);
      lsn += __shfl_xor(lsn, off); lcn += __shfl_xor(lcn, off);
    }
  }
  if (lane == 0) {
    const bool valid = (psum > 0.0f) && (nsum > 0.0f);
    rowloss[i] = valid ? (2.0f / BETA) * log1pf(psum) + (2.0f / ALPHA) * log1pf(nsum) : 0.0f;
    rowvalid[i] = valid ? 0.0f : 1.0f;
    if (lastw) { lacc[0] = lsp; lacc[1] = lcp; lacc[2] = lsn; lacc[3] = lcn; }
  }
}

__device__ __forceinline__ float block_sum(float v) {
  __shared__ float sh[4];
  #pragma unroll
  for (int off = 32; off > 0; off >>= 1) v += __shfl_down(v, off);
  if ((threadIdx.x & 63) == 0) sh[threadIdx.x >> 6] = v;
  __syncthreads();
  float r = sh[0] + sh[1] + sh[2] + sh[3];
  __syncthreads();
  return r;
}

__global__ __launch_bounds__(256) void finalize_k(
    const float* __restrict__ rowloss, const float* __restrict__ rowvalid,
    const float* __restrict__ lacc, float* __restrict__ out) {
  float lsum = 0.0f, inval = 0.0f;
  #pragma unroll
  for (int c = 0; c < 16; ++c) {
    const int i = c * 256 + threadIdx.x;
    lsum += rowloss[i];
    inval += rowvalid[i];
  }
  lsum = block_sum(lsum);
  inval = block_sum(inval);
  if (threadIdx.x == 0) {
    out[0] = lsum / (float)NROWS;
    out[1] = inval / (float)NROWS;
    out[2] = lacc[0] / fmaxf(lacc[1], 1.0f);
    out[3] = lacc[2] / fmaxf(lacc[3], 1.0f);
  }
}

extern "C" void kernel_launch(void* const* d_in, const int* in_sizes, int n_in,
                              void* d_out, int out_size, void* d_ws, size_t ws_size,
                              hipStream_t stream) {
  const float* X = (const float*)d_in[0];
  const int* tgt = (const int*)d_in[1];
  const float* marginp = (const float*)d_in[2];
  float* out = (float*)d_out;

  char* ws = (char*)d_ws;
  float* rowloss = (float*)ws;                    // @0     16 KB
  float* rowvalid = (float*)(ws + (16 << 10));    // @16K   16 KB
  float* lacc = (float*)(ws + (32 << 10));        // @32K   small
  unsigned short* Xb = (unsigned short*)(ws + (128 << 10));  // 4 MB
  unsigned short* simb = (unsigned short*)(ws + (128 << 10) + ((size_t)4 << 20));  // 32 MB

  convert_k<<<dim3(NROWS / 4), 256, 0, stream>>>(X, Xb);
  gemm_tri_store<<<dim3(NTRI), 256, 0, stream>>>(Xb, simb);
  rows_k<<<dim3(NROWS / 4), 256, 0, stream>>>(simb, tgt, marginp, rowloss, rowvalid, lacc);
  finalize_k<<<dim3(1), 256, 0, stream>>>(rowloss, rowvalid, lacc, out);
}

// Round 14
// 107.110 us; speedup vs baseline: 1.9892x; 1.0155x over previous
//
#include <hip/hip_runtime.h>
#include <hip/hip_bf16.h>
#include <math.h>

#define NROWS 4096
#define DDIM  512
#define BM    128
#define BK    64
#define NT    (DDIM / BK)              // 8 K-steps
#define NBLK  (NROWS / BM)             // 32
#define NTRI  (NBLK * (NBLK + 1) / 2)  // 528 upper-triangle tiles (528 % 8 == 0)

static constexpr float ALPHA = 10.0f;
static constexpr float BETA  = 2.0f;
static constexpr float BASE  = 0.5f;

typedef short bf16x8 __attribute__((ext_vector_type(8)));
typedef float f32x4 __attribute__((ext_vector_type(4)));

__device__ __forceinline__ unsigned f2bf(float f) {
  __hip_bfloat16 h = __float2bfloat16(f);  // RNE
  return (unsigned)*reinterpret_cast<unsigned short*>(&h);
}
__device__ __forceinline__ float bf2f(unsigned short u) {
  return __uint_as_float(((unsigned)u) << 16);
}

#define GLOAD_LDS16(g, l)                                              \
  __builtin_amdgcn_global_load_lds(                                    \
      (const __attribute__((address_space(1))) void*)(g),              \
      (__attribute__((address_space(3))) void*)(l), 16, 0, 0)

// ---- convert X f32 -> bf16 packed (wave-per-row) ----
__global__ __launch_bounds__(256) void convert_k(const float* __restrict__ X,
                                                 unsigned short* __restrict__ Xb) {
  const int wid = threadIdx.x >> 6, lane = threadIdx.x & 63;
  const int r = blockIdx.x * 4 + wid;
  const size_t base = (size_t)r * DDIM + lane * 8;
  const float4 v0 = *reinterpret_cast<const float4*>(X + base);
  const float4 v1 = *reinterpret_cast<const float4*>(X + base + 4);
  uint4 u;
  u.x = f2bf(v0.x) | (f2bf(v0.y) << 16);
  u.y = f2bf(v0.z) | (f2bf(v0.w) << 16);
  u.z = f2bf(v1.x) | (f2bf(v1.y) << 16);
  u.w = f2bf(v1.z) | (f2bf(v1.w) << 16);
  *reinterpret_cast<uint4*>(Xb + base) = u;
}

// ---- triangle 128x128 MFMA GEMM: R3-verified dbuf BK=64 prefetch loop +
//      R13-verified one-shot coalesced store epilogue (both orientations).
//      Diagonal elements stored as bf16 1.0 (R7/R12/R13-verified). ----
__global__ __launch_bounds__(256) void gemm_tri_store(
    const unsigned short* __restrict__ Xb, unsigned short* __restrict__ simb) {
  __shared__ unsigned short lds[2][2][BM * BK] __attribute__((aligned(16)));  // 64 KB

  // XCD-bijective swizzle (528 % 8 == 0)
  const int bswz = (blockIdx.x & 7) * (NTRI / 8) + (blockIdx.x >> 3);
  int kk0 = bswz, bi = 0;
  while (kk0 >= NBLK - bi) { kk0 -= NBLK - bi; ++bi; }
  const int bj = bi + kk0;
  const int i0 = bi * BM, j0 = bj * BM;
  const bool diagb = (bi == bj);

  const int tid = threadIdx.x;
  const int w = tid >> 6, lane = tid & 63;
  const int wr = w >> 1, wc = w & 1;
  const int g = lane >> 4, q = lane & 15;
  const char* Xbb = (const char*)Xb;

  f32x4 acc[4][4];
  #pragma unroll
  for (int m = 0; m < 4; ++m)
    #pragma unroll
    for (int n = 0; n < 4; ++n) acc[m][n] = (f32x4)0.0f;

  // stage tile t into dbuf 'buf' (pre-swizzled global src, linear LDS dst)
  #define STAGE(buf, t)                                                        \
    do {                                                                       \
      const int kb_ = (t) * (BK * 2);                                          \
      _Pragma("unroll")                                                        \
      for (int c_ = 0; c_ < 4; ++c_) {                                         \
        const int lin_ = (c_ * 256 + tid) * 16;                                \
        const int row_ = lin_ >> 7;                                            \
        const int col_ = lin_ & 127;                                           \
        const int scol_ = col_ ^ ((row_ & 7) << 4);                            \
        GLOAD_LDS16(Xbb + (size_t)(i0 + row_) * (DDIM * 2) + kb_ + scol_,      \
                    (char*)&lds[buf][0][0] + lin_);                            \
        if (!diagb)                                                            \
          GLOAD_LDS16(Xbb + (size_t)(j0 + row_) * (DDIM * 2) + kb_ + scol_,    \
                      (char*)&lds[buf][1][0] + lin_);                          \
      }                                                                        \
    } while (0)

  STAGE(0, 0);
  __syncthreads();  // prologue tile landed (vmcnt drained by barrier)
  int cur = 0;
  for (int t = 0; t < NT; ++t) {
    if (t + 1 < NT) STAGE(cur ^ 1, t + 1);  // issue next-tile loads first
    const char* Ab = (const char*)&lds[cur][0][0];
    const char* Bb = diagb ? Ab : (const char*)&lds[cur][1][0];
    #pragma unroll
    for (int kk = 0; kk < 2; ++kk) {
      bf16x8 a[4], b[4];
      #pragma unroll
      for (int fm = 0; fm < 4; ++fm) {
        const int row = wr * 64 + fm * 16 + q;
        const int colb = (kk * 64 + g * 16) ^ ((row & 7) << 4);
        a[fm] = *reinterpret_cast<const bf16x8*>(Ab + row * 128 + colb);
      }
      #pragma unroll
      for (int fn = 0; fn < 4; ++fn) {
        const int row = wc * 64 + fn * 16 + q;
        const int colb = (kk * 64 + g * 16) ^ ((row & 7) << 4);
        b[fn] = *reinterpret_cast<const bf16x8*>(Bb + row * 128 + colb);
      }
      #pragma unroll
      for (int fm = 0; fm < 4; ++fm)
        #pragma unroll
        for (int fn = 0; fn < 4; ++fn)
          acc[fm][fn] = __builtin_amdgcn_mfma_f32_16x16x32_bf16(a[fm], b[fn], acc[fm][fn], 0, 0, 0);
    }
    __syncthreads();  // drains vmcnt(0): next buffer staged; current reads done
    cur ^= 1;
  }

  // ---- one-shot store epilogue (R13): SV = 128 rows x 136 ushort (34.8 KB,
  //      overlays the dead staging buffers; final loop barrier protects) ----
  unsigned short* SV = &lds[0][0][0];

  // orientation 0: row-major tile -> simb[i0+row][j0+col]
  #pragma unroll
  for (int fm = 0; fm < 4; ++fm)
    #pragma unroll
    for (int reg = 0; reg < 4; ++reg) {
      const int rloc = wr * 64 + fm * 16 + g * 4 + reg;
      #pragma unroll
      for (int fn = 0; fn < 4; ++fn) {
        const int cloc = wc * 64 + fn * 16 + q;
        unsigned short v = (unsigned short)f2bf(acc[fm][fn][reg]);
        if (diagb && rloc == cloc) v = 0x3F80;  // diag = 1.0
        SV[rloc * 136 + cloc] = v;
      }
    }
  __syncthreads();
  #pragma unroll
  for (int rr = 0; rr < 8; ++rr) {
    const int s = rr * 256 + tid;
    const int row = s >> 4, cs = s & 15;
    const bf16x8 vv = *reinterpret_cast<const bf16x8*>(&SV[row * 136 + cs * 8]);
    *reinterpret_cast<bf16x8*>(simb + (size_t)(i0 + row) * NROWS + j0 + cs * 8) = vv;
  }

  if (!diagb) {
    __syncthreads();  // orient-0 reads complete before overwrite
    // orientation 1: transposed tile -> simb[j0+row][i0+col]; acc regs 0..3
    // are col-adjacent in the transposed view -> packed uint2 writes
    #pragma unroll
    for (int fn = 0; fn < 4; ++fn) {
      const int shrow = wc * 64 + fn * 16 + q;
      #pragma unroll
      for (int fm = 0; fm < 4; ++fm) {
        const int colR = wr * 64 + fm * 16 + g * 4;
        uint2 uu;
        uu.x = f2bf(acc[fm][fn][0]) | (f2bf(acc[fm][fn][1]) << 16);
        uu.y = f2bf(acc[fm][fn][2]) | (f2bf(acc[fm][fn][3]) << 16);
        *reinterpret_cast<uint2*>(&SV[shrow * 136 + colR]) = uu;
      }
    }
    __syncthreads();
    #pragma unroll
    for (int rr = 0; rr < 8; ++rr) {
      const int s = rr * 256 + tid;
      const int row = s >> 4, cs = s & 15;
      const bf16x8 vv = *reinterpret_cast<const bf16x8*>(&SV[row * 136 + cs * 8]);
      *reinterpret_cast<bf16x8*>(simb + (size_t)(j0 + row) * NROWS + i0 + cs * 8) = vv;
    }
  }
}

// ---- wave-per-row: read row once into regs; phase A min/max + class mask;
//      phase B exp-sums + last-row pre-mining stats. No atomics. (R7) ----
__global__ __launch_bounds__(256) void rows_k(
    const unsigned short* __restrict__ simb, const int* __restrict__ tgt,
    const float* __restrict__ marginp, float* __restrict__ rowloss,
    float* __restrict__ rowvalid, float* __restrict__ lacc) {
  __shared__ int tgl[NROWS];  // 16 KB
  const int tid = threadIdx.x;
  #pragma unroll
  for (int c = 0; c < 4; ++c)
    reinterpret_cast<int4*>(tgl)[tid + c * 256] =
        reinterpret_cast<const int4*>(tgt)[tid + c * 256];
  __syncthreads();

  const int wid = tid >> 6, lane = tid & 63;
  const int i = blockIdx.x * 4 + wid;
  const int ti = tgl[i];
  const unsigned short* row = simb + (size_t)i * NROWS;
  const bool lastw = (i == NROWS - 1);

  bf16x8 v[8];
  unsigned long long same = 0ull;
  float minp = INFINITY, maxn = -INFINITY;
  #pragma unroll
  for (int c = 0; c < 8; ++c) {
    const int j0 = c * 512 + lane * 8;
    v[c] = *reinterpret_cast<const bf16x8*>(row + j0);
    const int4 t0 = *reinterpret_cast<const int4*>(tgl + j0);
    const int4 t1 = *reinterpret_cast<const int4*>(tgl + j0 + 4);
    const int tj[8] = {t0.x, t0.y, t0.z, t0.w, t1.x, t1.y, t1.z, t1.w};
    #pragma unroll
    for (int e = 0; e < 8; ++e) {
      const float s = bf2f((unsigned short)v[c][e]);
      const bool sm = (tj[e] == ti);
      same |= (unsigned long long)sm << (c * 8 + e);
      if (sm) {
        if (s < 1.0f) minp = fminf(minp, s);
      } else {
        maxn = fmaxf(maxn, s);
      }
    }
  }
  #pragma unroll
  for (int off = 1; off < 64; off <<= 1) {
    minp = fminf(minp, __shfl_xor(minp, off));
    maxn = fmaxf(maxn, __shfl_xor(maxn, off));
  }

  const float margin = *marginp;
  float psum = 0.0f, nsum = 0.0f;
  float lsp = 0.0f, lcp = 0.0f, lsn = 0.0f, lcn = 0.0f;
  #pragma unroll
  for (int c = 0; c < 8; ++c) {
    #pragma unroll
    for (int e = 0; e < 8; ++e) {
      const float s = bf2f((unsigned short)v[c][e]);
      const bool sm = (same >> (c * 8 + e)) & 1ull;
      if (!sm) {
        if (s + margin - minp > 0.0f) nsum += __expf(ALPHA * (s - BASE));
        if (lastw) { lsn += s; lcn += 1.0f; }
      } else if (s < 1.0f) {
        if (maxn - s + margin > 0.0f) psum += __expf(-BETA * (s - BASE));
        if (lastw) { lsp += s; lcp += 1.0f; }
      }
    }
  }
  #pragma unroll
  for (int off = 1; off < 64; off <<= 1) {
    psum += __shfl_xor(psum, off);
    nsum += __shfl_xor(nsum, off);
  }
  if (lastw) {
    #pragma unroll
    for (int off = 1; off < 64; off <<= 1) {
      lsp += __shfl_xor(lsp, off); lcp += __shfl_xor(lcp, off);
      lsn += __shfl_xor(lsn, off); lcn += __shfl_xor(lcn, off);
    }
  }
  if (lane == 0) {
    const bool valid = (psum > 0.0f) && (nsum > 0.0f);
    rowloss[i] = valid ? (2.0f / BETA) * log1pf(psum) + (2.0f / ALPHA) * log1pf(nsum) : 0.0f;
    rowvalid[i] = valid ? 0.0f : 1.0f;
    if (lastw) { lacc[0] = lsp; lacc[1] = lcp; lacc[2] = lsn; lacc[3] = lcn; }
  }
}

__device__ __forceinline__ float block_sum(float v) {
  __shared__ float sh[4];
  #pragma unroll
  for (int off = 32; off > 0; off >>= 1) v += __shfl_down(v, off);
  if ((threadIdx.x & 63) == 0) sh[threadIdx.x >> 6] = v;
  __syncthreads();
  float r = sh[0] + sh[1] + sh[2] + sh[3];
  __syncthreads();
  return r;
}

__global__ __launch_bounds__(256) void finalize_k(
    const float* __restrict__ rowloss, const float* __restrict__ rowvalid,
    const float* __restrict__ lacc, float* __restrict__ out) {
  float lsum = 0.0f, inval = 0.0f;
  #pragma unroll
  for (int c = 0; c < 16; ++c) {
    const int i = c * 256 + threadIdx.x;
    lsum += rowloss[i];
    inval += rowvalid[i];
  }
  lsum = block_sum(lsum);
  inval = block_sum(inval);
  if (threadIdx.x == 0) {
    out[0] = lsum / (float)NROWS;
    out[1] = inval / (float)NROWS;
    out[2] = lacc[0] / fmaxf(lacc[1], 1.0f);
    out[3] = lacc[2] / fmaxf(lacc[3], 1.0f);
  }
}

extern "C" void kernel_launch(void* const* d_in, const int* in_sizes, int n_in,
                              void* d_out, int out_size, void* d_ws, size_t ws_size,
                              hipStream_t stream) {
  const float* X = (const float*)d_in[0];
  const int* tgt = (const int*)d_in[1];
  const float* marginp = (const float*)d_in[2];
  float* out = (float*)d_out;

  char* ws = (char*)d_ws;
  float* rowloss = (float*)ws;                    // @0     16 KB
  float* rowvalid = (float*)(ws + (16 << 10));    // @16K   16 KB
  float* lacc = (float*)(ws + (32 << 10));        // @32K   small
  unsigned short* Xb = (unsigned short*)(ws + (128 << 10));  // 4 MB
  unsigned short* simb = (unsigned short*)(ws + (128 << 10) + ((size_t)4 << 20));  // 32 MB

  convert_k<<<dim3(NROWS / 4), 256, 0, stream>>>(X, Xb);
  gemm_tri_store<<<dim3(NTRI), 256, 0, stream>>>(Xb, simb);
  rows_k<<<dim3(NROWS / 4), 256, 0, stream>>>(simb, tgt, marginp, rowloss, rowvalid, lacc);
  finalize_k<<<dim3(1), 256, 0, stream>>>(rowloss, rowvalid, lacc, out);
}